// Round 1
// baseline (99.126 us; speedup 1.0000x reference)
//
#include <hip/hip_runtime.h>
#include <math.h>

#define NGAMES 16384
#define BRD 64
#define CELLS 4096   // 64*64
#define THREADS 256
#define CHUNKS 4     // float4 chunks per thread; 4*4 = 16 cells/thread

__global__ __launch_bounds__(THREADS) void snake_step_kernel(
    const float* __restrict__ state,
    const int*   __restrict__ pos_prev,
    const int*   __restrict__ pos_cur,
    const int*   __restrict__ action,
    const float* __restrict__ noise,
    float*       __restrict__ out)
{
    const int g = blockIdx.x;
    const int t = threadIdx.x;
    const float* sg = state + (size_t)g * CELLS;
    float*       og = out   + (size_t)g * CELLS;

    // ---- scalar per-game logic (computed redundantly by all threads) ----
    const int pp0 = pos_prev[2 * g], pp1 = pos_prev[2 * g + 1];
    const int pc0 = pos_cur[2 * g],  pc1 = pos_cur[2 * g + 1];
    const int a = action[g];
    const int d0 = pc0 - pp0, d1 = pc1 - pp1;
    int nd0 = d0, nd1 = d1;
    if (a == 0)      { nd0 = -d1; nd1 =  d0; }   // left
    else if (a == 2) { nd0 =  d1; nd1 = -d0; }   // right
    int pn0 = pc0 + nd0, pn1 = pc1 + nd1;
    const bool outside = (pn0 < 0) | (pn0 >= BRD) | (pn1 < 0) | (pn1 >= BRD);
    pn0 = min(max(pn0, 0), BRD - 1);
    pn1 = min(max(pn1, 0), BRD - 1);
    const float cell = sg[pn0 * BRD + pn1];      // same addr for all lanes -> broadcast
    const bool dead    = outside | (cell > 0.0f);
    const bool feeding = (cell == -1.0f);
    const bool spawn   = dead | feeding;

    const int posc = dead ? (32 * BRD + 31) : (pc0 * BRD + pc1);
    const int posn = dead ? (32 * BRD + 32) : (pn0 * BRD + pn1);

    // ---- load this thread's 16 cells (coalesced float4) ----
    float s[16];
    float4* s4 = reinterpret_cast<float4*>(s);
    const float4* sg4 = reinterpret_cast<const float4*>(sg);
    #pragma unroll
    for (int k = 0; k < CHUNKS; ++k)
        s4[k] = sg4[t + k * THREADS];

    // ---- dead: zero board, then respawn cells (32,30)=1 (32,31)=2 (32,32)=1 ----
    if (dead) {
        #pragma unroll
        for (int k = 0; k < CHUNKS; ++k) {
            #pragma unroll
            for (int j = 0; j < 4; ++j) {
                const int idx = (t + k * THREADS) * 4 + j;
                float x = 0.0f;
                if (idx == 2078) x = 1.0f;       // (32,30)
                else if (idx == 2079) x = 2.0f;  // (32,31)
                else if (idx == 2080) x = 1.0f;  // (32,32)
                s[k * 4 + j] = x;
            }
        }
    }

    __shared__ float wv[THREADS / 64];
    __shared__ int   wi[THREADS / 64];
    __shared__ int   food_s;
    __shared__ float head_s;

    // ---- spawn: argmax(noise) over empty cells (block-uniform branch) ----
    int food = -1;
    if (spawn) {
        float bv = -INFINITY;
        int   bi = 0x7FFFFFFF;
        const float4* ng4 = reinterpret_cast<const float4*>(noise + (size_t)g * CELLS);
        #pragma unroll
        for (int k = 0; k < CHUNKS; ++k) {
            const float4 nv = ng4[t + k * THREADS];
            const float nf[4] = {nv.x, nv.y, nv.z, nv.w};
            #pragma unroll
            for (int j = 0; j < 4; ++j) {
                const int idx = (t + k * THREADS) * 4 + j;
                if (s[k * 4 + j] == 0.0f) {
                    const float n = nf[j];
                    if (n > bv || (n == bv && idx < bi)) { bv = n; bi = idx; }
                }
            }
        }
        // wave (64-lane) argmax reduce, tie -> smaller index
        #pragma unroll
        for (int off = 32; off > 0; off >>= 1) {
            const float ov = __shfl_xor(bv, off, 64);
            const int   oi = __shfl_xor(bi, off, 64);
            if (ov > bv || (ov == bv && oi < bi)) { bv = ov; bi = oi; }
        }
        const int wave = t >> 6;
        if ((t & 63) == 0) { wv[wave] = bv; wi[wave] = bi; }
        __syncthreads();
        if (t == 0) {
            float fv = wv[0]; int fi = wi[0];
            #pragma unroll
            for (int w = 1; w < THREADS / 64; ++w)
                if (wv[w] > fv || (wv[w] == fv && wi[w] < fi)) { fv = wv[w]; fi = wi[w]; }
            food_s = (fv == -INFINITY) ? 0 : fi;   // all -inf -> argmax = 0 (jnp semantics)
        }
        __syncthreads();
        food = food_s;
    }

    // ---- food placement + decrement (per-cell independent, order-safe) ----
    #pragma unroll
    for (int k = 0; k < CHUNKS; ++k) {
        #pragma unroll
        for (int j = 0; j < 4; ++j) {
            const int idx = (t + k * THREADS) * 4 + j;
            if (spawn && idx == food) s[k * 4 + j] = -1.0f;
            if (!feeding && s[k * 4 + j] > 0.0f) s[k * 4 + j] -= 1.0f;
        }
    }

    // ---- head read (after dec) broadcast, then head+1 write at pos_next ----
    #pragma unroll
    for (int k = 0; k < CHUNKS; ++k) {
        #pragma unroll
        for (int j = 0; j < 4; ++j) {
            const int idx = (t + k * THREADS) * 4 + j;
            if (idx == posc) head_s = s[k * 4 + j];
        }
    }
    __syncthreads();
    const float head = head_s;
    #pragma unroll
    for (int k = 0; k < CHUNKS; ++k) {
        #pragma unroll
        for (int j = 0; j < 4; ++j) {
            const int idx = (t + k * THREADS) * 4 + j;
            if (idx == posn) s[k * 4 + j] = head + 1.0f;
        }
    }

    // ---- store (coalesced float4) ----
    float4* og4 = reinterpret_cast<float4*>(og);
    #pragma unroll
    for (int k = 0; k < CHUNKS; ++k)
        og4[t + k * THREADS] = s4[k];
}

extern "C" void kernel_launch(void* const* d_in, const int* in_sizes, int n_in,
                              void* d_out, int out_size, void* d_ws, size_t ws_size,
                              hipStream_t stream) {
    const float* state    = (const float*)d_in[0];
    const int*   pos_prev = (const int*)d_in[1];
    const int*   pos_cur  = (const int*)d_in[2];
    const int*   action   = (const int*)d_in[3];
    const float* noise    = (const float*)d_in[4];
    float*       out      = (float*)d_out;

    snake_step_kernel<<<NGAMES, THREADS, 0, stream>>>(
        state, pos_prev, pos_cur, action, noise, out);
}

// Round 2
// 98.831 us; speedup vs baseline: 1.0030x; 1.0030x over previous
//
#include <hip/hip_runtime.h>
#include <math.h>

#define NGAMES 16384
#define BRD 64
#define CELLS 4096   // 64*64
#define THREADS 256
#define CHUNKS 4     // float4 chunks per thread; 4*4 = 16 cells/thread

__global__ __launch_bounds__(THREADS) void snake_step_kernel(
    const float* __restrict__ state,
    const int*   __restrict__ pos_prev,
    const int*   __restrict__ pos_cur,
    const int*   __restrict__ action,
    const float* __restrict__ noise,
    float*       __restrict__ out)
{
    const int g = blockIdx.x;
    const int t = threadIdx.x;
    const float* sg = state + (size_t)g * CELLS;
    float*       og = out   + (size_t)g * CELLS;

    // ---- scalar per-game logic (computed redundantly by all threads) ----
    const int pp0 = pos_prev[2 * g], pp1 = pos_prev[2 * g + 1];
    const int pc0 = pos_cur[2 * g],  pc1 = pos_cur[2 * g + 1];
    const int a = action[g];
    const int d0 = pc0 - pp0, d1 = pc1 - pp1;
    int nd0 = d0, nd1 = d1;
    if (a == 0)      { nd0 = -d1; nd1 =  d0; }   // left
    else if (a == 2) { nd0 =  d1; nd1 = -d0; }   // right
    int pn0 = pc0 + nd0, pn1 = pc1 + nd1;
    const bool outside = (pn0 < 0) | (pn0 >= BRD) | (pn1 < 0) | (pn1 >= BRD);
    pn0 = min(max(pn0, 0), BRD - 1);
    pn1 = min(max(pn1, 0), BRD - 1);

    // two INDEPENDENT broadcast loads (issued in parallel, no dependent chain)
    const float cellv = sg[pn0 * BRD + pn1];   // cell at pos_next (post-clip)
    const float curv  = sg[pc0 * BRD + pc1];   // cell at pos_cur (head value if !dead)

    const bool dead    = outside | (cellv > 0.0f);
    const bool feeding = (cellv == -1.0f);
    const bool spawn   = dead | feeding;

    const int posc = dead ? (32 * BRD + 31) : (pc0 * BRD + pc1);  // 2079 if dead
    const int posn = dead ? (32 * BRD + 32) : (pn0 * BRD + pn1);  // 2080 if dead

    // ---- load this thread's 16 cells (coalesced float4) ----
    float s[16];
    float4* s4 = reinterpret_cast<float4*>(s);
    const float4* sg4 = reinterpret_cast<const float4*>(sg);
    #pragma unroll
    for (int k = 0; k < CHUNKS; ++k)
        s4[k] = sg4[t + k * THREADS];

    // ---- dead: zero board, then respawn cells (32,30)=1 (32,31)=2 (32,32)=1 ----
    if (dead) {
        #pragma unroll
        for (int k = 0; k < CHUNKS; ++k) {
            #pragma unroll
            for (int j = 0; j < 4; ++j) {
                const int idx = (t + k * THREADS) * 4 + j;
                float x = 0.0f;
                if (idx == 2078) x = 1.0f;       // (32,30)
                else if (idx == 2079) x = 2.0f;  // (32,31)
                else if (idx == 2080) x = 1.0f;  // (32,32)
                s[k * 4 + j] = x;
            }
        }
    }

    __shared__ float wv[THREADS / 64];
    __shared__ int   wi[THREADS / 64];
    __shared__ int   food_s;

    // ---- spawn: argmax(noise) over empty cells (block-uniform branch,
    //      barriers legal; never taken on the bench inputs) ----
    int food = -1;
    if (spawn) {
        float bv = -INFINITY;
        int   bi = 0x7FFFFFFF;
        const float4* ng4 = reinterpret_cast<const float4*>(noise + (size_t)g * CELLS);
        #pragma unroll
        for (int k = 0; k < CHUNKS; ++k) {
            const float4 nv = ng4[t + k * THREADS];
            const float nf[4] = {nv.x, nv.y, nv.z, nv.w};
            #pragma unroll
            for (int j = 0; j < 4; ++j) {
                const int idx = (t + k * THREADS) * 4 + j;
                if (s[k * 4 + j] == 0.0f) {
                    const float n = nf[j];
                    if (n > bv || (n == bv && idx < bi)) { bv = n; bi = idx; }
                }
            }
        }
        // wave (64-lane) argmax reduce, tie -> smaller index
        #pragma unroll
        for (int off = 32; off > 0; off >>= 1) {
            const float ov = __shfl_xor(bv, off, 64);
            const int   oi = __shfl_xor(bi, off, 64);
            if (ov > bv || (ov == bv && oi < bi)) { bv = ov; bi = oi; }
        }
        const int wave = t >> 6;
        if ((t & 63) == 0) { wv[wave] = bv; wi[wave] = bi; }
        __syncthreads();
        if (t == 0) {
            float fv = wv[0]; int fi = wi[0];
            #pragma unroll
            for (int w = 1; w < THREADS / 64; ++w)
                if (wv[w] > fv || (wv[w] == fv && wi[w] < fi)) { fv = wv[w]; fi = wi[w]; }
            food_s = (fv == -INFINITY) ? 0 : fi;   // all -inf -> argmax = 0 (jnp semantics)
        }
        __syncthreads();
        food = food_s;
    }

    // ---- food placement + decrement (per-cell independent, order-safe) ----
    #pragma unroll
    for (int k = 0; k < CHUNKS; ++k) {
        #pragma unroll
        for (int j = 0; j < 4; ++j) {
            const int idx = (t + k * THREADS) * 4 + j;
            if (spawn && idx == food) s[k * 4 + j] = -1.0f;
            if (!feeding && s[k * 4 + j] > 0.0f) s[k * 4 + j] -= 1.0f;
        }
    }

    // ---- head value computed SCALARLY by every thread (no LDS, no barrier):
    //      value at posc after {dead-transform, food placement, decrement} ----
    float headv = dead ? 2.0f : curv;            // (32,31)=2.0 after respawn
    if (spawn && food == posc) headv = -1.0f;    // food overwrote head cell
    if (!feeding && headv > 0.0f) headv -= 1.0f; // decrement pass
    // head+1 write at pos_next (only the owning thread's cell changes)
    #pragma unroll
    for (int k = 0; k < CHUNKS; ++k) {
        #pragma unroll
        for (int j = 0; j < 4; ++j) {
            const int idx = (t + k * THREADS) * 4 + j;
            if (idx == posn) s[k * 4 + j] = headv + 1.0f;
        }
    }

    // ---- store (coalesced float4) ----
    float4* og4 = reinterpret_cast<float4*>(og);
    #pragma unroll
    for (int k = 0; k < CHUNKS; ++k)
        og4[t + k * THREADS] = s4[k];
}

extern "C" void kernel_launch(void* const* d_in, const int* in_sizes, int n_in,
                              void* d_out, int out_size, void* d_ws, size_t ws_size,
                              hipStream_t stream) {
    const float* state    = (const float*)d_in[0];
    const int*   pos_prev = (const int*)d_in[1];
    const int*   pos_cur  = (const int*)d_in[2];
    const int*   action   = (const int*)d_in[3];
    const float* noise    = (const float*)d_in[4];
    float*       out      = (float*)d_out;

    snake_step_kernel<<<NGAMES, THREADS, 0, stream>>>(
        state, pos_prev, pos_cur, action, noise, out);
}

// Round 4
// 69.142 us; speedup vs baseline: 1.4337x; 1.4294x over previous
//
#include <hip/hip_runtime.h>
#include <math.h>

#define NGAMES 16384
#define BRD 64
#define CELLS 4096   // 64*64
#define THREADS 128
#define CHUNKS 8     // 8 float4 per thread; 128*8*4 = 4096 cells
#define NWAVES (THREADS / 64)

typedef float f4 __attribute__((ext_vector_type(4)));   // native vector: OK for nontemporal builtins

__global__ __launch_bounds__(THREADS) void snake_step_kernel(
    const float* __restrict__ state,
    const int*   __restrict__ pos_prev,
    const int*   __restrict__ pos_cur,
    const int*   __restrict__ action,
    const float* __restrict__ noise,
    float*       __restrict__ out)
{
    const int g = blockIdx.x;
    const int t = threadIdx.x;
    const float* sg = state + (size_t)g * CELLS;
    float*       og = out   + (size_t)g * CELLS;

    __shared__ float wv[NWAVES];
    __shared__ int   wi[NWAVES];
    __shared__ int   food_s;

    // ---- scalar per-game logic (pure int math after tiny loads) ----
    const int pp0 = pos_prev[2 * g], pp1 = pos_prev[2 * g + 1];
    const int pc0 = pos_cur[2 * g],  pc1 = pos_cur[2 * g + 1];
    const int a = action[g];
    const int d0 = pc0 - pp0, d1 = pc1 - pp1;
    int nd0 = d0, nd1 = d1;
    if (a == 0)      { nd0 = -d1; nd1 =  d0; }   // left
    else if (a == 2) { nd0 =  d1; nd1 = -d0; }   // right
    int pn0 = pc0 + nd0, pn1 = pc1 + nd1;
    const bool outside = (pn0 < 0) | (pn0 >= BRD) | (pn1 < 0) | (pn1 >= BRD);
    pn0 = min(max(pn0, 0), BRD - 1);
    pn1 = min(max(pn1, 0), BRD - 1);
    const int posn_spec = pn0 * BRD + pn1;       // pos_next assuming !dead
    const int posc_live = pc0 * BRD + pc1;

    // broadcast loads (in flight while bulk loads stream)
    const float cellv = sg[posn_spec];
    const float curv  = sg[posc_live];

    // ---- bulk load (independent of broadcasts) ----
    f4 v[CHUNKS];
    const f4* sg4 = reinterpret_cast<const f4*>(sg);
    #pragma unroll
    for (int k = 0; k < CHUNKS; ++k)
        v[k] = sg4[t + k * THREADS];

    // ---- speculative transform: assume !dead && !feeding (-> decrement positives) ----
    #pragma unroll
    for (int k = 0; k < CHUNKS; ++k) {
        #pragma unroll
        for (int j = 0; j < 4; ++j)
            v[k][j] = (v[k][j] > 0.0f) ? v[k][j] - 1.0f : v[k][j];
    }

    const int  headF   = posn_spec >> 2;            // float4 index of head cell
    const int  headK   = headF >> 7;                // = headF / THREADS
    const bool ownHead = (t == (headF & (THREADS - 1)));

    // ---- speculative stores: everything except the head chunk of its owner ----
    f4* og4 = reinterpret_cast<f4*>(og);
    #pragma unroll
    for (int k = 0; k < CHUNKS; ++k)
        if (!(ownHead && k == headK))
            __builtin_nontemporal_store(v[k], &og4[t + k * THREADS]);

    // ---- resolve gates (stores above did NOT wait on these) ----
    const bool dead    = outside | (cellv > 0.0f);
    const bool feeding = (cellv == -1.0f);
    const bool rare    = dead | feeding;            // == spawn

    if (!rare) {
        // common path: owner merges head+1 into its deferred chunk and stores it
        if (ownHead) {
            const float headv = (curv > 0.0f) ? curv - 1.0f : curv;  // post-dec head
            const float hv = headv + 1.0f;
            const int j = posn_spec & 3;
            #pragma unroll
            for (int k = 0; k < CHUNKS; ++k)
                if (k == headK) {
                    f4 w = v[k];
                    w[j] = hv;
                    __builtin_nontemporal_store(w, &og4[t + k * THREADS]);
                }
        }
        return;
    }

    // ================= rare path (dead or feeding; block-uniform) =================
    __syncthreads();   // keep waves together before full rewrite

    // reload original state (L2-hot)
    float s[CHUNKS * 4];
    f4* s4 = reinterpret_cast<f4*>(s);
    #pragma unroll
    for (int k = 0; k < CHUNKS; ++k)
        s4[k] = sg4[t + k * THREADS];

    // dead: zero board, respawn (32,30)=1 (32,31)=2 (32,32)=1
    if (dead) {
        #pragma unroll
        for (int k = 0; k < CHUNKS; ++k) {
            #pragma unroll
            for (int j = 0; j < 4; ++j) {
                const int idx = (t + k * THREADS) * 4 + j;
                float x = 0.0f;
                if (idx == 2078) x = 1.0f;
                else if (idx == 2079) x = 2.0f;
                else if (idx == 2080) x = 1.0f;
                s[k * 4 + j] = x;
            }
        }
    }

    // spawn (== rare): argmax(noise) over empty cells
    {
        float bv = -INFINITY;
        int   bi = 0x7FFFFFFF;
        const f4* ng4 = reinterpret_cast<const f4*>(noise + (size_t)g * CELLS);
        #pragma unroll
        for (int k = 0; k < CHUNKS; ++k) {
            const f4 nv = ng4[t + k * THREADS];
            #pragma unroll
            for (int j = 0; j < 4; ++j) {
                const int idx = (t + k * THREADS) * 4 + j;
                if (s[k * 4 + j] == 0.0f) {
                    const float n = nv[j];
                    if (n > bv || (n == bv && idx < bi)) { bv = n; bi = idx; }
                }
            }
        }
        #pragma unroll
        for (int off = 32; off > 0; off >>= 1) {
            const float ov = __shfl_xor(bv, off, 64);
            const int   oi = __shfl_xor(bi, off, 64);
            if (ov > bv || (ov == bv && oi < bi)) { bv = ov; bi = oi; }
        }
        const int wave = t >> 6;
        if ((t & 63) == 0) { wv[wave] = bv; wi[wave] = bi; }
        __syncthreads();
        if (t == 0) {
            float fv = wv[0]; int fi = wi[0];
            #pragma unroll
            for (int w = 1; w < NWAVES; ++w)
                if (wv[w] > fv || (wv[w] == fv && wi[w] < fi)) { fv = wv[w]; fi = wi[w]; }
            food_s = (fv == -INFINITY) ? 0 : fi;   // all -inf -> argmax = 0 (jnp semantics)
        }
        __syncthreads();
    }
    const int food = food_s;

    // food placement + decrement
    #pragma unroll
    for (int k = 0; k < CHUNKS; ++k) {
        #pragma unroll
        for (int j = 0; j < 4; ++j) {
            const int idx = (t + k * THREADS) * 4 + j;
            if (idx == food) s[k * 4 + j] = -1.0f;
            if (!feeding && s[k * 4 + j] > 0.0f) s[k * 4 + j] -= 1.0f;
        }
    }

    // head value (scalar, every thread)
    const int posc = dead ? (32 * BRD + 31) : posc_live;   // 2079
    const int posn = dead ? (32 * BRD + 32) : posn_spec;   // 2080
    float headv = dead ? 2.0f : curv;
    if (food == posc) headv = -1.0f;
    if (!feeding && headv > 0.0f) headv -= 1.0f;
    const float hv = headv + 1.0f;

    // full rewrite with head merged (every address rewritten by its original writer)
    const int posnF = posn >> 2, posnJ = posn & 3;
    #pragma unroll
    for (int k = 0; k < CHUNKS; ++k) {
        f4 w = s4[k];
        if ((t + k * THREADS) == posnF) w[posnJ] = hv;
        og4[t + k * THREADS] = w;
    }
}

extern "C" void kernel_launch(void* const* d_in, const int* in_sizes, int n_in,
                              void* d_out, int out_size, void* d_ws, size_t ws_size,
                              hipStream_t stream) {
    const float* state    = (const float*)d_in[0];
    const int*   pos_prev = (const int*)d_in[1];
    const int*   pos_cur  = (const int*)d_in[2];
    const int*   action   = (const int*)d_in[3];
    const float* noise    = (const float*)d_in[4];
    float*       out      = (float*)d_out;

    snake_step_kernel<<<NGAMES, THREADS, 0, stream>>>(
        state, pos_prev, pos_cur, action, noise, out);
}